// Round 14
// baseline (2658.267 us; speedup 1.0000x reference)
//
#include <hip/hip_runtime.h>
#include <hip/hip_fp16.h>
#include <stdint.h>

// ---------------------------------------------------------------------------
// TreeSimpleGRU on MI355X: parent-owner polling worker (measured ~2300us,
// byte-identical since R14) + fused prep + BARRIER-MINIMAL single-block scan.
//
// Round 18: R17's memset fold was null -> prepA's wall time is its block-0
// serial scan (32 chunks x 3 barriers + serial thread-0 prefix ~70us).
// R16's MULTI-block scan crashed the container; the safe restructure is
// within the single block: (1) each thread owns a contiguous 32-edge
// segment, flags -> register bitmask + count; (2) one shfl_up wave scan +
// 16-entry shared prefix -> exclusive offsets; (3) per-thread scatter of
// group_start/node_group. 2 barriers instead of ~96, zero cross-block
// protocol, all loops compile-time bounded. k_bulkB / k_worker / launcher
// byte-identical to the passing R17 binary (2629us).
// ---------------------------------------------------------------------------

#define ROWS 470      // 450 GRU rows + 20 attention rows
#define AST  480      // A_all / R_all row stride (halves)
#define WST  512      // UW / WK column stride (uint32 words)
#define NP2  76       // padded packed-pair columns (75 real + 1 zero)
#define KST  80       // K_pack stride in words (75 packed pairs + pad)
#define NPAIR 75      // 150 halves / 2

static __device__ __forceinline__ float fdot2f(uint32_t w, uint32_t x, float acc){
#if __has_builtin(__builtin_amdgcn_fdot2)
  typedef _Float16 h2v __attribute__((ext_vector_type(2)));
  return __builtin_amdgcn_fdot2(__builtin_bit_cast(h2v,w), __builtin_bit_cast(h2v,x), acc, false);
#else
  __half2 a = __builtin_bit_cast(__half2,w), b = __builtin_bit_cast(__half2,x);
  return acc + __low2float(a)*__low2float(b) + __high2float(a)*__high2float(b);
#endif
}
static __device__ __forceinline__ uint4 ld4(const uint32_t* __restrict__ P, int t, int q){
  return make_uint4(P[(4*q+0)*WST+t], P[(4*q+1)*WST+t], P[(4*q+2)*WST+t], P[(4*q+3)*WST+t]);
}
static __device__ __forceinline__ void pinu4(uint4 &v){
  asm volatile("" : "+v"(v.x), "+v"(v.y), "+v"(v.z), "+v"(v.w));
}
static __device__ __forceinline__ float sigm(float x){ return 1.f/(1.f+__expf(-x)); }
static __device__ __forceinline__ float tanhx(float x){ float e=__expf(2.f*x); return 1.f - 2.f/(e+1.f); }
static __device__ __forceinline__ uint32_t packh(float a, float b){
  return (uint32_t)__half_as_ushort(__float2half(a)) | ((uint32_t)__half_as_ushort(__float2half(b))<<16);
}
static __device__ __forceinline__ uint32_t aloadw(const uint32_t* p){
  return __hip_atomic_load(p, __ATOMIC_RELAXED, __HIP_MEMORY_SCOPE_AGENT);
}
static __device__ __forceinline__ void astoreh(unsigned short* p, unsigned short v){
  __hip_atomic_store(p, v, __ATOMIC_RELAXED, __HIP_MEMORY_SCOPE_AGENT);
}
// a finite fp16 is never 0xFFFF (-NaN) -> each half self-validates
static __device__ __forceinline__ bool validw(uint32_t w){
  return ((w & 0xffffu) != 0xffffu) && ((w >> 16) != 0xffffu);
}

#define DECL_W(W, P) \
  uint4 W##0=ld4(P,t,0),  W##1=ld4(P,t,1),  W##2=ld4(P,t,2),  W##3=ld4(P,t,3), \
        W##4=ld4(P,t,4),  W##5=ld4(P,t,5),  W##6=ld4(P,t,6),  W##7=ld4(P,t,7), \
        W##8=ld4(P,t,8),  W##9=ld4(P,t,9),  W##10=ld4(P,t,10),W##11=ld4(P,t,11), \
        W##12=ld4(P,t,12),W##13=ld4(P,t,13),W##14=ld4(P,t,14),W##15=ld4(P,t,15), \
        W##16=ld4(P,t,16),W##17=ld4(P,t,17),W##18=ld4(P,t,18);

#define PIN_W(W) \
  pinu4(W##0);  pinu4(W##1);  pinu4(W##2);  pinu4(W##3);  pinu4(W##4); \
  pinu4(W##5);  pinu4(W##6);  pinu4(W##7);  pinu4(W##8);  pinu4(W##9); \
  pinu4(W##10); pinu4(W##11); pinu4(W##12); pinu4(W##13); pinu4(W##14); \
  pinu4(W##15); pinu4(W##16); pinu4(W##17); pinu4(W##18);

// 4-way split accumulator chains (R8 codegen); PRE added at the END.
#define DOT1(I, W, S) \
  _a0 = fdot2f(W##I.x, S[I].x, _a0); _a1 = fdot2f(W##I.y, S[I].y, _a1); \
  _a2 = fdot2f(W##I.z, S[I].z, _a2); _a3 = fdot2f(W##I.w, S[I].w, _a3);

#define DOT_ALL(P, W, S) { \
  float _a0 = 0.f, _a1 = 0.f, _a2 = 0.f, _a3 = 0.f; \
  DOT1(0,W,S)  DOT1(1,W,S)  DOT1(2,W,S)  DOT1(3,W,S)  DOT1(4,W,S) \
  DOT1(5,W,S)  DOT1(6,W,S)  DOT1(7,W,S)  DOT1(8,W,S)  DOT1(9,W,S) \
  DOT1(10,W,S) DOT1(11,W,S) DOT1(12,W,S) DOT1(13,W,S) DOT1(14,W,S) \
  DOT1(15,W,S) DOT1(16,W,S) DOT1(17,W,S) DOT1(18,W,S) \
  P = (P) + ((_a0 + _a1) + (_a2 + _a3)); \
}

// one GRU_AT edge step. PUBP: publish row (ushort*) or null; OUTP: d_out or
// null; SLOT: kbuf slot to release (or -1). Publish/out issue the moment _hn
// exists — zero post-compute latency.
#define DO_STEP(PRE, SRC, PUBP, OUTP, SLOT) { \
  float _pre = (PRE); \
  const uint4* _s4 = (const uint4*)(SRC); \
  DOT_ALL(_pre, wk, _s4); \
  if (rowOK) act[t] = (t < 300) ? sigm(_pre) : tanhx(_pre); \
  __syncthreads(); \
  if (t < 150) { \
    float _s = atba_v; \
    _Pragma("unroll") \
    for (int _j = 0; _j < 20; ++_j) _s += was[_j]*act[450 + _j]; \
    float _a = sigm(_s); \
    float _z = act[t], _r = act[150 + t], _ht = act[300 + t]; \
    float _m  = _r*hreg + (1.f - _z)*_ht; \
    float _hn = _a*_m + (1.f - _a)*hreg; \
    hreg = _hn; \
    unsigned short _hb = __half_as_ushort(__float2half(_hn)); \
    ((unsigned short*)h_pack)[t] = _hb; \
    unsigned short* _pp = (PUBP); \
    if (_pp) astoreh(_pp + t, _hb); \
    float* _op = (OUTP); \
    if (_op) _op[t] = _hn; \
  } \
  if ((SLOT) >= 0 && t == 256) vstaged[(SLOT)] = 0; \
  __syncthreads(); \
}

#define CALC_UH(OUT) { \
  float _x = 0.f; \
  const uint4* _h4 = (const uint4*)h_pack; \
  DOT_ALL(_x, uw, _h4); \
  OUT = _x; \
}

// ---------------------------------------------------------------------------
// KA: fused prep. block 0 = barrier-minimal edge scan, block 1 = uh_leaf,
// blocks >=2 = weight transposes/packing + edge scatter + K_pack 0xFF init.
// ---------------------------------------------------------------------------
__global__ __launch_bounds__(1024, 1)
void k_prepA(const int* __restrict__ edges, int E,
             const float* __restrict__ node_U, const float* __restrict__ node_W,
             const float* __restrict__ at_Wb,  const float* __restrict__ leaf_W,
             const float* __restrict__ leaf_U, const float* __restrict__ leaf_h,
             const float* __restrict__ leaf_b, float* __restrict__ uh_leaf,
             uint32_t* __restrict__ UW, uint32_t* __restrict__ WK,
             float* __restrict__ NWT, float* __restrict__ LWT, float* __restrict__ RWT,
             int* __restrict__ parent_of, int* __restrict__ has_child,
             int* __restrict__ group_start, int* __restrict__ ctrl,
             int* __restrict__ node_group, uint32_t* __restrict__ K_pack, int K4)
{
  const int t = threadIdx.x;           // 1024
  if (blockIdx.x == 0) {
    // ---- barrier-minimal scan: thread t owns edges [t*32, t*32+32) ----
    __shared__ int wtot[16], woff[16];
    const int lane = t & 63, wave = t >> 6;
    const int base_i = t*32;
    uint32_t fl = 0; int cnt = 0;
    #pragma unroll
    for (int k = 0; k < 32; ++k) {
      int i = base_i + k;
      if (i < E) {
        bool flag = (i == 0) || (edges[2*(i-1)] != edges[2*i]);
        if (flag) { fl |= (1u << k); ++cnt; }
      }
    }
    // wave-level inclusive scan of per-thread counts
    int inc = cnt;
    #pragma unroll
    for (int o = 1; o < 64; o <<= 1) {
      int v = __shfl_up(inc, o, 64);
      if (lane >= o) inc += v;
    }
    if (lane == 63) wtot[wave] = inc;
    __syncthreads();
    if (t == 0) {
      int run = 0;
      #pragma unroll
      for (int w = 0; w < 16; ++w) { woff[w] = run; run += wtot[w]; }
      ctrl[1] = run; group_start[run] = E;
    }
    __syncthreads();
    int g = woff[wave] + inc - cnt;     // exclusive prefix for this thread
    #pragma unroll
    for (int k = 0; k < 32; ++k) {
      if (fl & (1u << k)) {
        int i = base_i + k;
        group_start[g] = i;
        node_group[edges[2*i]] = g;
        ++g;
      }
    }
    return;
  }
  if (blockIdx.x == 1) {
    // ---- uh_leaf[450] = leaf_U @ leaf_h + leaf_b ----
    if (t < 450) {
      float s = leaf_b[t];
      for (int n = 0; n < 150; ++n) s += leaf_U[t*150 + n]*leaf_h[n];
      uh_leaf[t] = s;
    }
    return;
  }
  // ---- bulk prep ----
  int o = (blockIdx.x - 2)*1024 + t;
  if (o < E) {
    int p = edges[2*o], c = edges[2*o+1];
    parent_of[c] = p; has_child[p] = 1;
    if (o == 0) parent_of[0] = -1;
    return;
  }
  o -= E;
  if (o < NP2*WST) {               // UW: packed f16 pairs of node_U, [i][row]
    int i = o/WST, j = o%WST;
    uint32_t v = 0u;
    if (i < NPAIR && j < 450) v = packh(node_U[j*150 + 2*i], node_U[j*150 + 2*i + 1]);
    UW[o] = v; return;
  }
  o -= NP2*WST;
  if (o < NP2*WST) {               // WK: packed W_k rows + attention rows
    int i = o/WST, j = o%WST;
    uint32_t v = 0u;
    if (i < NPAIR) {
      if (j < 450)      v = packh(node_W[j*490 + 300 + 2*i], node_W[j*490 + 301 + 2*i]);
      else if (j < 470) v = packh(at_Wb[(j-450)*490 + 300 + 2*i], at_Wb[(j-450)*490 + 301 + 2*i]);
    }
    WK[o] = v; return;
  }
  o -= NP2*WST;
  if (o < 320*ROWS) {              // NWT[i][r]: word(0..299)+tag(->cols 470..489)
    int i = o/ROWS, r = o%ROWS;
    int col = (i < 300) ? i : 470 + (i - 300);
    NWT[o] = (r < 450) ? node_W[r*490 + col] : at_Wb[(r-450)*490 + col];
    return;
  }
  o -= 320*ROWS;
  if (o < 320*450) {               // LWT[i][r]: leaf_W transposed
    int i = o/450, r = o%450;
    LWT[o] = leaf_W[r*320 + i];
    return;
  }
  o -= 320*450;
  if (o < 20*ROWS) {               // RWT[i][r]: rel cols 450..469
    int i = o/ROWS, r = o%ROWS;
    RWT[o] = (r < 450) ? node_W[r*490 + 450 + i] : at_Wb[(r-450)*490 + 450 + i];
    return;
  }
  o -= 20*ROWS;
  if (o < K4) {                    // K_pack sentinel init (uint4-wide)
    ((uint4*)K_pack)[o] = make_uint4(~0u, ~0u, ~0u, ~0u);
    return;
  }
}

// ---------------------------------------------------------------------------
// KB: fused bulk compute. Block ranges: [0,SB) = A_all rows (static),
// [SB,SB+LB) = leaves, [SB+LB,..) = R_all rows. LDS is a 40KB union.
// ---------------------------------------------------------------------------
__global__ __launch_bounds__(512, 1)
void k_bulkB(const int* __restrict__ edges, const int* __restrict__ group_start,
             const int* __restrict__ ctrl,
             const float* __restrict__ w_emb, const float* __restrict__ tag_emb,
             const float* __restrict__ NWT, const float* __restrict__ node_b,
             const float* __restrict__ at_bb, __half* __restrict__ A_all,
             const int* __restrict__ leaf_ids, const float* __restrict__ LWT,
             const float* __restrict__ uh_leaf, const float* __restrict__ leaf_h,
             uint32_t* __restrict__ K_pack, int L,
             const float* __restrict__ rel_emb, const float* __restrict__ RWT_g,
             __half* __restrict__ R_all, int N, int SB, int LB)
{
  __shared__ __align__(16) char smem[40448];
  const int t = threadIdx.x;           // 512
  const int bid = blockIdx.x;

  if (bid < SB) {
    // ================= A_all rows for internal nodes =================
    float* xs = (float*)smem;                       // 320*16 floats
    int*   pl = (int*)(xs + 320*16);                // 16 ints
    int NG = ctrl[1];
    int base = bid*16; if (base >= NG) return;
    int cnt = min(16, NG - base);
    if (t < cnt) pl[t] = edges[2*group_start[base + t]];
    __syncthreads();
    for (int idx = t; idx < cnt*320; idx += 512) {
      int nl = idx/320, i = idx%320; int n = pl[nl];
      xs[i*16 + nl] = (i < 300) ? w_emb[(size_t)n*300 + i] : tag_emb[(size_t)n*20 + (i-300)];
    }
    __syncthreads();
    if (t < ROWS) {
      float acc[16];
      #pragma unroll
      for (int j = 0; j < 16; ++j) acc[j] = 0.f;
      for (int i = 0; i < 320; ++i) {
        float w = NWT[i*ROWS + t];
        const float4* x4 = (const float4*)(xs + i*16);
        float4 xa = x4[0], xb = x4[1], xc = x4[2], xd = x4[3];
        acc[0]+=w*xa.x; acc[1]+=w*xa.y; acc[2]+=w*xa.z; acc[3]+=w*xa.w;
        acc[4]+=w*xb.x; acc[5]+=w*xb.y; acc[6]+=w*xb.z; acc[7]+=w*xb.w;
        acc[8]+=w*xc.x; acc[9]+=w*xc.y; acc[10]+=w*xc.z; acc[11]+=w*xc.w;
        acc[12]+=w*xd.x; acc[13]+=w*xd.y; acc[14]+=w*xd.z; acc[15]+=w*xd.w;
      }
      float bias = (t < 450) ? node_b[t] : at_bb[t-450];
      for (int j = 0; j < cnt; ++j)
        A_all[(size_t)pl[j]*AST + t] = __float2half(acc[j] + bias);
    }
    return;
  }

  if (bid < SB + LB) {
    // ======================== leaves ========================
    float* xs   = (float*)smem;                     // 320*8 floats
    float* actl = xs + 320*8;                       // 8*450 floats
    int*   lid  = (int*)(actl + 8*450);             // 8 ints
    float* lh   = (float*)(lid + 8);                // 150 floats
    int base = (bid - SB)*8; if (base >= L) return;
    int cnt = min(8, L - base);
    if (t < cnt) lid[t] = leaf_ids[base + t];
    if (t < 150) lh[t] = leaf_h[t];
    __syncthreads();
    for (int idx = t; idx < cnt*320; idx += 512) {
      int nl = idx/320, i = idx%320; int n = lid[nl];
      xs[i*8 + nl] = (i < 300) ? w_emb[(size_t)n*300 + i] : tag_emb[(size_t)n*20 + (i-300)];
    }
    __syncthreads();
    if (t < 450) {
      float a0=0,a1=0,a2=0,a3=0,a4=0,a5=0,a6=0,a7=0;
      for (int i = 0; i < 320; ++i) {
        float w = LWT[i*450 + t];
        const float4* x4 = (const float4*)(xs + i*8);
        float4 xa = x4[0], xb = x4[1];
        a0 += w*xa.x; a1 += w*xa.y; a2 += w*xa.z; a3 += w*xa.w;
        a4 += w*xb.x; a5 += w*xb.y; a6 += w*xb.z; a7 += w*xb.w;
      }
      float acc[8] = {a0,a1,a2,a3,a4,a5,a6,a7};
      float uh = uh_leaf[t];
      for (int j = 0; j < cnt; ++j) {
        float pre = acc[j] + uh;
        actl[j*450 + t] = (t < 300) ? sigm(pre) : tanhx(pre);
      }
    }
    __syncthreads();
    for (int idx = t; idx < cnt*150; idx += 512) {
      int nl = idx/150, m = idx%150;
      float z = actl[nl*450 + m], r = actl[nl*450 + 150 + m], ht = actl[nl*450 + 300 + m];
      float kv = r*lh[m] + (1.f - z)*ht;
      ((unsigned short*)(K_pack + (size_t)lid[nl]*KST))[m] = __half_as_ushort(__float2half(kv));
    }
    return;
  }

  // ======================== R_all rows ========================
  {
    float* rw = (float*)smem;                       // 20*470 floats
    float* xs = rw + 20*ROWS;                       // 20*32 floats
    for (int idx = t; idx < 20*ROWS; idx += 512) rw[idx] = RWT_g[idx];
    int base = (bid - SB - LB)*32;
    if (base >= N) return;
    int cnt = min(32, N - base);
    for (int idx = t; idx < cnt*20; idx += 512) {
      int nl = idx/20, i = idx%20;
      xs[i*32 + nl] = rel_emb[(size_t)(base+nl)*20 + i];
    }
    __syncthreads();
    if (t < ROWS) {
      float w[20];
      #pragma unroll
      for (int i = 0; i < 20; ++i) w[i] = rw[i*ROWS + t];
      for (int j = 0; j < cnt; ++j) {
        float acc = 0.f;
        #pragma unroll
        for (int i = 0; i < 20; ++i) acc += w[i]*xs[i*32 + j];
        R_all[(size_t)(base+j)*AST + t] = __float2half(acc);
      }
    }
  }
}

// ---------------------------------------------------------------------------
// K6: parent-owner persistent worker — BYTE-IDENTICAL to the measured R14-R17
// kernel (~2300 us). At every child iteration e, waves 1..7 make ONE bounded
// staging attempt for children e+1..e+7; wave 0 polls the current child.
// Publish/out inline in DO_STEP (16-bit sentinel halves).
// ---------------------------------------------------------------------------
__global__ __launch_bounds__(512, 1)
void k_worker(const int* __restrict__ edges,
              const float* __restrict__ at_Wa, const float* __restrict__ at_ba,
              const uint32_t* __restrict__ UW, const uint32_t* __restrict__ WK,
              const __half* __restrict__ A_all, const __half* __restrict__ R_all,
              uint32_t* __restrict__ K_pack,
              int* __restrict__ ctrl, const int* __restrict__ group_start,
              const int* __restrict__ parent_of, const int* __restrict__ node_group,
              const int* __restrict__ has_child, float* __restrict__ d_out)
{
  const int t = threadIdx.x;           // 512; rows 0..469 valid
  const bool rowOK = (t < ROWS);

  __shared__ __align__(16) uint32_t h_pack[80];
  __shared__ __align__(16) uint32_t kbuf[8*76];   // 8 slots of packed-pair child K
  __shared__ float act[472];
  __shared__ float was[20];
  __shared__ int   s_g;
  volatile __shared__ int vstaged[8];

  DECL_W(wk, WK)
  DECL_W(uw, UW)
  PIN_W(wk)
  PIN_W(uw)

  if (t >= NPAIR && t < 80) h_pack[t] = 0u;       // zero pad halves
  if (t < 8) { vstaged[t] = 0; kbuf[t*76 + 75] = 0u; }  // pad word per slot
  if (t < 20) was[t] = at_Wa[t];
  const float atba_v = at_ba[0];
  const int NG = ctrl[1];
  float hreg = 0.f;
  __syncthreads();

  for (;;) {
    if (t == 0) s_g = atomicAdd(&ctrl[0], 1);
    __syncthreads();
    const int g = s_g;
    if (g >= NG) break;
    const int gs = group_start[g], ge = group_start[g+1];
    const int p  = edges[2*gs];
    if (ge - gs == 1 && has_child[edges[2*gs + 1]]) continue;  // absorbed by child's chain

    // ---- climb metadata + absorb-operand prefetch (hidden under steps) ----
    int  r = parent_of[p];
    bool single = false;
    if (r >= 0) {
      const int gr = node_group[r];
      single = (group_start[gr+1] - group_start[gr] == 1);
    }
    const float aSt = rowOK ? __half2float(A_all[(size_t)p*AST + t]) : 0.f;
    float aN = 0.f, rN = 0.f;
    if (single && rowOK) {
      aN = __half2float(A_all[(size_t)r*AST + t]);
      rN = __half2float(R_all[(size_t)p*AST + t]);
    }
    if (t < 150) hreg = 0.f;
    float uh = 0.f;

    // ---- group task: children ascending; per-iteration sibling staging ----
    for (int e = gs; e < ge; ++e) {
      const int slot = (e - gs) & 7;
      const int c = edges[2*e + 1];
      const float rSt = rowOK ? __half2float(R_all[(size_t)c*AST + t]) : 0.f;
      {
        const int w = t >> 6, l = t & 63;
        if (w >= 1) {
          // ONE bounded attempt per iteration: wave w tries child e+w.
          const int j = e + w;
          if (j < ge) {
            const int slj = (j - gs) & 7;
            if (!vstaged[slj]) {
              const int cj = edges[2*j + 1];
              const uint32_t* rowp = K_pack + (size_t)cj*KST;
              uint32_t a = aloadw(rowp + l);
              uint32_t b = (l < 11) ? aloadw(rowp + 64 + l) : 0u;
              bool ok = validw(a) && (l >= 11 || validw(b));
              if (__all(ok)) {
                uint32_t* kb = kbuf + slj*76;
                kb[l] = a; if (l < 11) kb[64 + l] = b;
                if (l == 0) vstaged[slj] = 1;
              }
            }
          }
        } else if (!vstaged[slot]) {
          // wave 0: blocking poll-with-data on the current child (R8).
          const uint32_t* rowp = K_pack + (size_t)c*KST;
          uint32_t* kb = kbuf + slot*76;
          long spins = 0;
          for (;;) {
            uint32_t a = aloadw(rowp + l);
            uint32_t b = (l < 11) ? aloadw(rowp + 64 + l) : 0u;
            bool ok = validw(a) && (l >= 11 || validw(b));
            if (__all(ok)) { kb[l] = a; if (l < 11) kb[64 + l] = b; break; }
            __builtin_amdgcn_s_sleep(1);
            if (++spins > 50000000L) break;   // safety valve
          }
        }
      }
      __syncthreads();                 // kbuf[slot] visible to all waves
      unsigned short* pubp = nullptr; float* outp = nullptr;
      if (e + 1 == ge) {
        if (p == 0) outp = d_out;
        else if (!single) pubp = (unsigned short*)(K_pack + (size_t)p*KST);
      }
      DO_STEP(aSt + rSt + uh, kbuf + slot*76, pubp, outp, slot)
      if (e + 1 < ge) { CALC_UH(uh) } else uh = 0.f;
    }

    // ---- climb through single-child ancestors (publish/out are inline) ----
    int q = p;
    for (;;) {
      if (q == 0) break;                 // d_out written inline
      if (!single) break;                // publish written inline
      // absorb edge (r,q): kc = fresh h in LDS; prefetch next level meanwhile
      const int r2p = parent_of[r];
      bool s2 = false;
      if (r2p >= 0) {
        const int gr2 = node_group[r2p];
        s2 = (group_start[gr2+1] - group_start[gr2] == 1);
      }
      float aN2 = 0.f, rN2 = 0.f;
      if (s2 && rowOK) {
        aN2 = __half2float(A_all[(size_t)r2p*AST + t]);
        rN2 = __half2float(R_all[(size_t)r*AST + t]);
      }
      if (t < 150) hreg = 0.f;
      unsigned short* pubp = nullptr; float* outp = nullptr;
      if (r == 0) outp = d_out;
      else if (!s2) pubp = (unsigned short*)(K_pack + (size_t)r*KST);
      DO_STEP(aN + rN, h_pack, pubp, outp, -1)
      q = r; r = r2p; single = s2; aN = aN2; rN = rN2;
    }
  }
}

// ---------------------------------------------------------------------------
extern "C" void kernel_launch(void* const* d_in, const int* in_sizes, int n_in,
                              void* d_out, int out_size, void* d_ws, size_t ws_size,
                              hipStream_t stream)
{
  const float* w_emb   = (const float*)d_in[0];
  const float* tag_emb = (const float*)d_in[1];
  const float* rel_emb = (const float*)d_in[2];
  const float* leaf_h  = (const float*)d_in[3];
  const float* leaf_W  = (const float*)d_in[4];
  const float* leaf_U  = (const float*)d_in[5];
  const float* leaf_b  = (const float*)d_in[6];
  const float* node_W  = (const float*)d_in[7];
  const float* node_U  = (const float*)d_in[8];
  const float* node_b  = (const float*)d_in[9];
  const float* at_Wb   = (const float*)d_in[10];
  const float* at_bb   = (const float*)d_in[11];
  const float* at_Wa   = (const float*)d_in[12];
  const float* at_ba   = (const float*)d_in[13];
  const int*   edges   = (const int*)d_in[14];
  const int*   leaf_ids= (const int*)d_in[15];
  float* out = (float*)d_out;

  const int N = in_sizes[0]/300;
  const int E = in_sizes[14]/2;
  const int L = in_sizes[15];

  char* ws = (char*)d_ws;
  size_t off = 0;
  auto take = [&](size_t bytes) -> char* {
    char* p = ws + off;
    off = (off + bytes + 255) & ~(size_t)255;
    return p;
  };
  size_t zbytes = 256 + (size_t)4*N;           // ctrl + has_child
  char* zbase       = take(zbytes);
  int*  ctrl        = (int*)zbase;             // [0]=pop counter, [1]=n_groups
  int*  has_child   = (int*)(zbase + 256);
  int*  parent_of   = (int*)take((size_t)4*N);
  int*  node_group  = (int*)take((size_t)4*N);
  int*  group_start = (int*)take((size_t)4*(N+1));
  uint32_t* UW      = (uint32_t*)take((size_t)4*NP2*WST);
  uint32_t* WK      = (uint32_t*)take((size_t)4*NP2*WST);
  float* NWT        = (float*)take((size_t)4*320*ROWS);
  float* LWT        = (float*)take((size_t)4*320*450);
  float* RWT        = (float*)take((size_t)4*20*ROWS);
  float* uh_leaf    = (float*)take((size_t)4*456);
  __half* A_all     = (__half*)take((size_t)2*((size_t)N*AST + 64));
  __half* R_all     = (__half*)take((size_t)2*((size_t)N*AST + 64));
  uint32_t* K_pack  = (uint32_t*)take((size_t)4*(size_t)N*KST);
  (void)ws_size; (void)n_in; (void)out_size;

  hipMemsetAsync(zbase, 0, zbytes, stream);

  const int K4  = (N*KST)/4;                   // K_pack uint4-init items
  const int TOT = E + NP2*WST + NP2*WST + 320*ROWS + 320*450 + 20*ROWS + K4;
  const int GA  = 2 + (TOT + 1023)/1024;
  k_prepA<<<GA, 1024, 0, stream>>>(edges, E, node_U, node_W, at_Wb, leaf_W,
                                   leaf_U, leaf_h, leaf_b, uh_leaf,
                                   UW, WK, NWT, LWT, RWT, parent_of, has_child,
                                   group_start, ctrl, node_group, K_pack, K4);

  const int SB = (N + 15)/16;          // static blocks (covers NG <= N groups)
  const int LB = (L + 7)/8;            // leaf blocks
  const int RB = (N + 31)/32;          // rel blocks
  k_bulkB<<<SB + LB + RB, 512, 0, stream>>>(edges, group_start, ctrl,
                                            w_emb, tag_emb, NWT, node_b, at_bb, A_all,
                                            leaf_ids, LWT, uh_leaf, leaf_h, K_pack, L,
                                            rel_emb, RWT, R_all, N, SB, LB);

  k_worker<<<256, 512, 0, stream>>>(edges, at_Wa, at_ba, UW, WK, A_all, R_all,
                                    K_pack, ctrl, group_start, parent_of,
                                    node_group, has_child, out);
}

// Round 15
// 2624.486 us; speedup vs baseline: 1.0129x; 1.0129x over previous
//
#include <hip/hip_runtime.h>
#include <hip/hip_fp16.h>
#include <stdint.h>

// ---------------------------------------------------------------------------
// TreeSimpleGRU on MI355X — FINAL (best-measured configuration, R15 binary,
// 2627 us total / 2287 us worker).
//
// Convergence summary:
//  * Worker: parent-owner polling + half-granular sentinel handoff (16-bit
//    inline publish fired inside DO_STEP's elementwise phase) + per-iteration
//    bounded sibling staging. Invariant at ~2290 us across 8 structural
//    experiments (claiming, 2x slots, wide u64 handoff, fast polling, XCD
//    pinning+dual publish, sibling staging variants) — all null or negative.
//    The binding constraint is the agent-scope publish->poll round-trip
//    (~1.5-2us) x ~630 cross-WG dependency hops on the tree's critical path;
//    per-XCD L2 non-coherence forces every hop through the MALL.
//  * Prep: fused to 2 kernels (A: scan|uh_leaf|bulk-transposes;
//    B: static|leaf|rel). Three restructuring rounds converged at ~2630+-30
//    total — the residue is launch gaps + bulkB work, not scan time.
// ---------------------------------------------------------------------------

#define ROWS 470      // 450 GRU rows + 20 attention rows
#define AST  480      // A_all / R_all row stride (halves)
#define WST  512      // UW / WK column stride (uint32 words)
#define NP2  76       // padded packed-pair columns (75 real + 1 zero)
#define KST  80       // K_pack stride in words (75 packed pairs + pad)
#define NPAIR 75      // 150 halves / 2

static __device__ __forceinline__ float fdot2f(uint32_t w, uint32_t x, float acc){
#if __has_builtin(__builtin_amdgcn_fdot2)
  typedef _Float16 h2v __attribute__((ext_vector_type(2)));
  return __builtin_amdgcn_fdot2(__builtin_bit_cast(h2v,w), __builtin_bit_cast(h2v,x), acc, false);
#else
  __half2 a = __builtin_bit_cast(__half2,w), b = __builtin_bit_cast(__half2,x);
  return acc + __low2float(a)*__low2float(b) + __high2float(a)*__high2float(b);
#endif
}
static __device__ __forceinline__ uint4 ld4(const uint32_t* __restrict__ P, int t, int q){
  return make_uint4(P[(4*q+0)*WST+t], P[(4*q+1)*WST+t], P[(4*q+2)*WST+t], P[(4*q+3)*WST+t]);
}
static __device__ __forceinline__ void pinu4(uint4 &v){
  asm volatile("" : "+v"(v.x), "+v"(v.y), "+v"(v.z), "+v"(v.w));
}
static __device__ __forceinline__ float sigm(float x){ return 1.f/(1.f+__expf(-x)); }
static __device__ __forceinline__ float tanhx(float x){ float e=__expf(2.f*x); return 1.f - 2.f/(e+1.f); }
static __device__ __forceinline__ uint32_t packh(float a, float b){
  return (uint32_t)__half_as_ushort(__float2half(a)) | ((uint32_t)__half_as_ushort(__float2half(b))<<16);
}
static __device__ __forceinline__ uint32_t aloadw(const uint32_t* p){
  return __hip_atomic_load(p, __ATOMIC_RELAXED, __HIP_MEMORY_SCOPE_AGENT);
}
static __device__ __forceinline__ void astoreh(unsigned short* p, unsigned short v){
  __hip_atomic_store(p, v, __ATOMIC_RELAXED, __HIP_MEMORY_SCOPE_AGENT);
}
// a finite fp16 is never 0xFFFF (-NaN) -> each half self-validates
static __device__ __forceinline__ bool validw(uint32_t w){
  return ((w & 0xffffu) != 0xffffu) && ((w >> 16) != 0xffffu);
}

#define DECL_W(W, P) \
  uint4 W##0=ld4(P,t,0),  W##1=ld4(P,t,1),  W##2=ld4(P,t,2),  W##3=ld4(P,t,3), \
        W##4=ld4(P,t,4),  W##5=ld4(P,t,5),  W##6=ld4(P,t,6),  W##7=ld4(P,t,7), \
        W##8=ld4(P,t,8),  W##9=ld4(P,t,9),  W##10=ld4(P,t,10),W##11=ld4(P,t,11), \
        W##12=ld4(P,t,12),W##13=ld4(P,t,13),W##14=ld4(P,t,14),W##15=ld4(P,t,15), \
        W##16=ld4(P,t,16),W##17=ld4(P,t,17),W##18=ld4(P,t,18);

#define PIN_W(W) \
  pinu4(W##0);  pinu4(W##1);  pinu4(W##2);  pinu4(W##3);  pinu4(W##4); \
  pinu4(W##5);  pinu4(W##6);  pinu4(W##7);  pinu4(W##8);  pinu4(W##9); \
  pinu4(W##10); pinu4(W##11); pinu4(W##12); pinu4(W##13); pinu4(W##14); \
  pinu4(W##15); pinu4(W##16); pinu4(W##17); pinu4(W##18);

// 4-way split accumulator chains; PRE added at the END so row loads overlap.
#define DOT1(I, W, S) \
  _a0 = fdot2f(W##I.x, S[I].x, _a0); _a1 = fdot2f(W##I.y, S[I].y, _a1); \
  _a2 = fdot2f(W##I.z, S[I].z, _a2); _a3 = fdot2f(W##I.w, S[I].w, _a3);

#define DOT_ALL(P, W, S) { \
  float _a0 = 0.f, _a1 = 0.f, _a2 = 0.f, _a3 = 0.f; \
  DOT1(0,W,S)  DOT1(1,W,S)  DOT1(2,W,S)  DOT1(3,W,S)  DOT1(4,W,S) \
  DOT1(5,W,S)  DOT1(6,W,S)  DOT1(7,W,S)  DOT1(8,W,S)  DOT1(9,W,S) \
  DOT1(10,W,S) DOT1(11,W,S) DOT1(12,W,S) DOT1(13,W,S) DOT1(14,W,S) \
  DOT1(15,W,S) DOT1(16,W,S) DOT1(17,W,S) DOT1(18,W,S) \
  P = (P) + ((_a0 + _a1) + (_a2 + _a3)); \
}

// one GRU_AT edge step. PUBP: publish row (ushort*) or null; OUTP: d_out or
// null; SLOT: kbuf slot to release (or -1). Publish/out issue the moment _hn
// exists — zero post-compute latency.
#define DO_STEP(PRE, SRC, PUBP, OUTP, SLOT) { \
  float _pre = (PRE); \
  const uint4* _s4 = (const uint4*)(SRC); \
  DOT_ALL(_pre, wk, _s4); \
  if (rowOK) act[t] = (t < 300) ? sigm(_pre) : tanhx(_pre); \
  __syncthreads(); \
  if (t < 150) { \
    float _s = atba_v; \
    _Pragma("unroll") \
    for (int _j = 0; _j < 20; ++_j) _s += was[_j]*act[450 + _j]; \
    float _a = sigm(_s); \
    float _z = act[t], _r = act[150 + t], _ht = act[300 + t]; \
    float _m  = _r*hreg + (1.f - _z)*_ht; \
    float _hn = _a*_m + (1.f - _a)*hreg; \
    hreg = _hn; \
    unsigned short _hb = __half_as_ushort(__float2half(_hn)); \
    ((unsigned short*)h_pack)[t] = _hb; \
    unsigned short* _pp = (PUBP); \
    if (_pp) astoreh(_pp + t, _hb); \
    float* _op = (OUTP); \
    if (_op) _op[t] = _hn; \
  } \
  if ((SLOT) >= 0 && t == 256) vstaged[(SLOT)] = 0; \
  __syncthreads(); \
}

#define CALC_UH(OUT) { \
  float _x = 0.f; \
  const uint4* _h4 = (const uint4*)h_pack; \
  DOT_ALL(_x, uw, _h4); \
  OUT = _x; \
}

// ---------------------------------------------------------------------------
// KA: fused prep. block 0 = edge scan (groups + node_group), block 1 =
// uh_leaf, blocks >=2 = weight transposes/packing + per-edge scatter.
// All three parts are mutually independent.
// ---------------------------------------------------------------------------
__global__ __launch_bounds__(1024, 1)
void k_prepA(const int* __restrict__ edges, int E,
             const float* __restrict__ node_U, const float* __restrict__ node_W,
             const float* __restrict__ at_Wb,  const float* __restrict__ leaf_W,
             const float* __restrict__ leaf_U, const float* __restrict__ leaf_h,
             const float* __restrict__ leaf_b, float* __restrict__ uh_leaf,
             uint32_t* __restrict__ UW, uint32_t* __restrict__ WK,
             float* __restrict__ NWT, float* __restrict__ LWT, float* __restrict__ RWT,
             int* __restrict__ parent_of, int* __restrict__ has_child,
             int* __restrict__ group_start, int* __restrict__ ctrl,
             int* __restrict__ node_group)
{
  const int t = threadIdx.x;           // 1024
  if (blockIdx.x == 0) {
    // ---- edge scan -> group boundaries + node_group map ----
    __shared__ int warp_cnt[16];
    __shared__ int wbase[16];
    __shared__ int base_s;
    if (t == 0) base_s = 0;
    __syncthreads();
    for (int chunk = 0; chunk < E; chunk += 1024) {
      int i = chunk + t;
      bool flag = false;
      if (i < E) flag = (i == 0) || (edges[2*(i-1)] != edges[2*i]);
      unsigned long long m = __ballot(flag ? 1 : 0);
      int wave = t >> 6, lane = t & 63;
      if (lane == 0) warp_cnt[wave] = __popcll(m);
      __syncthreads();
      if (t == 0) {
        int run = base_s;
        for (int w = 0; w < 16; ++w) { wbase[w] = run; run += warp_cnt[w]; }
        base_s = run;
      }
      __syncthreads();
      if (flag) {
        int g = wbase[wave] + __popcll(m & ((1ull << lane) - 1ull));
        group_start[g] = i;
      }
      __syncthreads();
    }
    if (t == 0) { ctrl[1] = base_s; group_start[base_s] = E; }
    __syncthreads();
    int NG = base_s;
    for (int g = t; g < NG; g += 1024) node_group[edges[2*group_start[g]]] = g;
    return;
  }
  if (blockIdx.x == 1) {
    // ---- uh_leaf[450] = leaf_U @ leaf_h + leaf_b ----
    if (t < 450) {
      float s = leaf_b[t];
      for (int n = 0; n < 150; ++n) s += leaf_U[t*150 + n]*leaf_h[n];
      uh_leaf[t] = s;
    }
    return;
  }
  // ---- bulk prep ----
  int o = (blockIdx.x - 2)*1024 + t;
  if (o < E) {
    int p = edges[2*o], c = edges[2*o+1];
    parent_of[c] = p; has_child[p] = 1;
    if (o == 0) parent_of[0] = -1;
    return;
  }
  o -= E;
  if (o < NP2*WST) {               // UW: packed f16 pairs of node_U, [i][row]
    int i = o/WST, j = o%WST;
    uint32_t v = 0u;
    if (i < NPAIR && j < 450) v = packh(node_U[j*150 + 2*i], node_U[j*150 + 2*i + 1]);
    UW[o] = v; return;
  }
  o -= NP2*WST;
  if (o < NP2*WST) {               // WK: packed W_k rows + attention rows
    int i = o/WST, j = o%WST;
    uint32_t v = 0u;
    if (i < NPAIR) {
      if (j < 450)      v = packh(node_W[j*490 + 300 + 2*i], node_W[j*490 + 301 + 2*i]);
      else if (j < 470) v = packh(at_Wb[(j-450)*490 + 300 + 2*i], at_Wb[(j-450)*490 + 301 + 2*i]);
    }
    WK[o] = v; return;
  }
  o -= NP2*WST;
  if (o < 320*ROWS) {              // NWT[i][r]: word(0..299)+tag(->cols 470..489)
    int i = o/ROWS, r = o%ROWS;
    int col = (i < 300) ? i : 470 + (i - 300);
    NWT[o] = (r < 450) ? node_W[r*490 + col] : at_Wb[(r-450)*490 + col];
    return;
  }
  o -= 320*ROWS;
  if (o < 320*450) {               // LWT[i][r]: leaf_W transposed
    int i = o/450, r = o%450;
    LWT[o] = leaf_W[r*320 + i];
    return;
  }
  o -= 320*450;
  if (o < 20*ROWS) {               // RWT[i][r]: rel cols 450..469
    int i = o/ROWS, r = o%ROWS;
    RWT[o] = (r < 450) ? node_W[r*490 + 450 + i] : at_Wb[(r-450)*490 + 450 + i];
    return;
  }
}

// ---------------------------------------------------------------------------
// KB: fused bulk compute. Block ranges: [0,SB) = A_all rows (static),
// [SB,SB+LB) = leaves, [SB+LB,..) = R_all rows. LDS is a 40KB union.
// ---------------------------------------------------------------------------
__global__ __launch_bounds__(512, 1)
void k_bulkB(const int* __restrict__ edges, const int* __restrict__ group_start,
             const int* __restrict__ ctrl,
             const float* __restrict__ w_emb, const float* __restrict__ tag_emb,
             const float* __restrict__ NWT, const float* __restrict__ node_b,
             const float* __restrict__ at_bb, __half* __restrict__ A_all,
             const int* __restrict__ leaf_ids, const float* __restrict__ LWT,
             const float* __restrict__ uh_leaf, const float* __restrict__ leaf_h,
             uint32_t* __restrict__ K_pack, int L,
             const float* __restrict__ rel_emb, const float* __restrict__ RWT_g,
             __half* __restrict__ R_all, int N, int SB, int LB)
{
  __shared__ __align__(16) char smem[40448];
  const int t = threadIdx.x;           // 512
  const int bid = blockIdx.x;

  if (bid < SB) {
    // ================= A_all rows for internal nodes =================
    float* xs = (float*)smem;                       // 320*16 floats
    int*   pl = (int*)(xs + 320*16);                // 16 ints
    int NG = ctrl[1];
    int base = bid*16; if (base >= NG) return;
    int cnt = min(16, NG - base);
    if (t < cnt) pl[t] = edges[2*group_start[base + t]];
    __syncthreads();
    for (int idx = t; idx < cnt*320; idx += 512) {
      int nl = idx/320, i = idx%320; int n = pl[nl];
      xs[i*16 + nl] = (i < 300) ? w_emb[(size_t)n*300 + i] : tag_emb[(size_t)n*20 + (i-300)];
    }
    __syncthreads();
    if (t < ROWS) {
      float acc[16];
      #pragma unroll
      for (int j = 0; j < 16; ++j) acc[j] = 0.f;
      for (int i = 0; i < 320; ++i) {
        float w = NWT[i*ROWS + t];
        const float4* x4 = (const float4*)(xs + i*16);
        float4 xa = x4[0], xb = x4[1], xc = x4[2], xd = x4[3];
        acc[0]+=w*xa.x; acc[1]+=w*xa.y; acc[2]+=w*xa.z; acc[3]+=w*xa.w;
        acc[4]+=w*xb.x; acc[5]+=w*xb.y; acc[6]+=w*xb.z; acc[7]+=w*xb.w;
        acc[8]+=w*xc.x; acc[9]+=w*xc.y; acc[10]+=w*xc.z; acc[11]+=w*xc.w;
        acc[12]+=w*xd.x; acc[13]+=w*xd.y; acc[14]+=w*xd.z; acc[15]+=w*xd.w;
      }
      float bias = (t < 450) ? node_b[t] : at_bb[t-450];
      for (int j = 0; j < cnt; ++j)
        A_all[(size_t)pl[j]*AST + t] = __float2half(acc[j] + bias);
    }
    return;
  }

  if (bid < SB + LB) {
    // ======================== leaves ========================
    float* xs   = (float*)smem;                     // 320*8 floats
    float* actl = xs + 320*8;                       // 8*450 floats
    int*   lid  = (int*)(actl + 8*450);             // 8 ints
    float* lh   = (float*)(lid + 8);                // 150 floats
    int base = (bid - SB)*8; if (base >= L) return;
    int cnt = min(8, L - base);
    if (t < cnt) lid[t] = leaf_ids[base + t];
    if (t < 150) lh[t] = leaf_h[t];
    __syncthreads();
    for (int idx = t; idx < cnt*320; idx += 512) {
      int nl = idx/320, i = idx%320; int n = lid[nl];
      xs[i*8 + nl] = (i < 300) ? w_emb[(size_t)n*300 + i] : tag_emb[(size_t)n*20 + (i-300)];
    }
    __syncthreads();
    if (t < 450) {
      float a0=0,a1=0,a2=0,a3=0,a4=0,a5=0,a6=0,a7=0;
      for (int i = 0; i < 320; ++i) {
        float w = LWT[i*450 + t];
        const float4* x4 = (const float4*)(xs + i*8);
        float4 xa = x4[0], xb = x4[1];
        a0 += w*xa.x; a1 += w*xa.y; a2 += w*xa.z; a3 += w*xa.w;
        a4 += w*xb.x; a5 += w*xb.y; a6 += w*xb.z; a7 += w*xb.w;
      }
      float acc[8] = {a0,a1,a2,a3,a4,a5,a6,a7};
      float uh = uh_leaf[t];
      for (int j = 0; j < cnt; ++j) {
        float pre = acc[j] + uh;
        actl[j*450 + t] = (t < 300) ? sigm(pre) : tanhx(pre);
      }
    }
    __syncthreads();
    for (int idx = t; idx < cnt*150; idx += 512) {
      int nl = idx/150, m = idx%150;
      float z = actl[nl*450 + m], r = actl[nl*450 + 150 + m], ht = actl[nl*450 + 300 + m];
      float kv = r*lh[m] + (1.f - z)*ht;
      ((unsigned short*)(K_pack + (size_t)lid[nl]*KST))[m] = __half_as_ushort(__float2half(kv));
    }
    return;
  }

  // ======================== R_all rows ========================
  {
    float* rw = (float*)smem;                       // 20*470 floats
    float* xs = rw + 20*ROWS;                       // 20*32 floats
    for (int idx = t; idx < 20*ROWS; idx += 512) rw[idx] = RWT_g[idx];
    int base = (bid - SB - LB)*32;
    if (base >= N) return;
    int cnt = min(32, N - base);
    for (int idx = t; idx < cnt*20; idx += 512) {
      int nl = idx/20, i = idx%20;
      xs[i*32 + nl] = rel_emb[(size_t)(base+nl)*20 + i];
    }
    __syncthreads();
    if (t < ROWS) {
      float w[20];
      #pragma unroll
      for (int i = 0; i < 20; ++i) w[i] = rw[i*ROWS + t];
      for (int j = 0; j < cnt; ++j) {
        float acc = 0.f;
        #pragma unroll
        for (int i = 0; i < 20; ++i) acc += w[i]*xs[i*32 + j];
        R_all[(size_t)(base+j)*AST + t] = __float2half(acc);
      }
    }
  }
}

// ---------------------------------------------------------------------------
// K6: parent-owner persistent worker — BYTE-IDENTICAL to the measured R14-R18
// kernel (~2290 us). At every child iteration e, waves 1..7 make ONE bounded
// staging attempt for children e+1..e+7; wave 0 polls the current child.
// Publish/out inline in DO_STEP (16-bit sentinel halves).
// ---------------------------------------------------------------------------
__global__ __launch_bounds__(512, 1)
void k_worker(const int* __restrict__ edges,
              const float* __restrict__ at_Wa, const float* __restrict__ at_ba,
              const uint32_t* __restrict__ UW, const uint32_t* __restrict__ WK,
              const __half* __restrict__ A_all, const __half* __restrict__ R_all,
              uint32_t* __restrict__ K_pack,
              int* __restrict__ ctrl, const int* __restrict__ group_start,
              const int* __restrict__ parent_of, const int* __restrict__ node_group,
              const int* __restrict__ has_child, float* __restrict__ d_out)
{
  const int t = threadIdx.x;           // 512; rows 0..469 valid
  const bool rowOK = (t < ROWS);

  __shared__ __align__(16) uint32_t h_pack[80];
  __shared__ __align__(16) uint32_t kbuf[8*76];   // 8 slots of packed-pair child K
  __shared__ float act[472];
  __shared__ float was[20];
  __shared__ int   s_g;
  volatile __shared__ int vstaged[8];

  DECL_W(wk, WK)
  DECL_W(uw, UW)
  PIN_W(wk)
  PIN_W(uw)

  if (t >= NPAIR && t < 80) h_pack[t] = 0u;       // zero pad halves
  if (t < 8) { vstaged[t] = 0; kbuf[t*76 + 75] = 0u; }  // pad word per slot
  if (t < 20) was[t] = at_Wa[t];
  const float atba_v = at_ba[0];
  const int NG = ctrl[1];
  float hreg = 0.f;
  __syncthreads();

  for (;;) {
    if (t == 0) s_g = atomicAdd(&ctrl[0], 1);
    __syncthreads();
    const int g = s_g;
    if (g >= NG) break;
    const int gs = group_start[g], ge = group_start[g+1];
    const int p  = edges[2*gs];
    if (ge - gs == 1 && has_child[edges[2*gs + 1]]) continue;  // absorbed by child's chain

    // ---- climb metadata + absorb-operand prefetch (hidden under steps) ----
    int  r = parent_of[p];
    bool single = false;
    if (r >= 0) {
      const int gr = node_group[r];
      single = (group_start[gr+1] - group_start[gr] == 1);
    }
    const float aSt = rowOK ? __half2float(A_all[(size_t)p*AST + t]) : 0.f;
    float aN = 0.f, rN = 0.f;
    if (single && rowOK) {
      aN = __half2float(A_all[(size_t)r*AST + t]);
      rN = __half2float(R_all[(size_t)p*AST + t]);
    }
    if (t < 150) hreg = 0.f;
    float uh = 0.f;

    // ---- group task: children ascending; per-iteration sibling staging ----
    for (int e = gs; e < ge; ++e) {
      const int slot = (e - gs) & 7;
      const int c = edges[2*e + 1];
      const float rSt = rowOK ? __half2float(R_all[(size_t)c*AST + t]) : 0.f;
      {
        const int w = t >> 6, l = t & 63;
        if (w >= 1) {
          // ONE bounded attempt per iteration: wave w tries child e+w.
          const int j = e + w;
          if (j < ge) {
            const int slj = (j - gs) & 7;
            if (!vstaged[slj]) {
              const int cj = edges[2*j + 1];
              const uint32_t* rowp = K_pack + (size_t)cj*KST;
              uint32_t a = aloadw(rowp + l);
              uint32_t b = (l < 11) ? aloadw(rowp + 64 + l) : 0u;
              bool ok = validw(a) && (l >= 11 || validw(b));
              if (__all(ok)) {
                uint32_t* kb = kbuf + slj*76;
                kb[l] = a; if (l < 11) kb[64 + l] = b;
                if (l == 0) vstaged[slj] = 1;
              }
            }
          }
        } else if (!vstaged[slot]) {
          // wave 0: blocking poll-with-data on the current child (R8).
          const uint32_t* rowp = K_pack + (size_t)c*KST;
          uint32_t* kb = kbuf + slot*76;
          long spins = 0;
          for (;;) {
            uint32_t a = aloadw(rowp + l);
            uint32_t b = (l < 11) ? aloadw(rowp + 64 + l) : 0u;
            bool ok = validw(a) && (l >= 11 || validw(b));
            if (__all(ok)) { kb[l] = a; if (l < 11) kb[64 + l] = b; break; }
            __builtin_amdgcn_s_sleep(1);
            if (++spins > 50000000L) break;   // safety valve
          }
        }
      }
      __syncthreads();                 // kbuf[slot] visible to all waves
      unsigned short* pubp = nullptr; float* outp = nullptr;
      if (e + 1 == ge) {
        if (p == 0) outp = d_out;
        else if (!single) pubp = (unsigned short*)(K_pack + (size_t)p*KST);
      }
      DO_STEP(aSt + rSt + uh, kbuf + slot*76, pubp, outp, slot)
      if (e + 1 < ge) { CALC_UH(uh) } else uh = 0.f;
    }

    // ---- climb through single-child ancestors (publish/out are inline) ----
    int q = p;
    for (;;) {
      if (q == 0) break;                 // d_out written inline
      if (!single) break;                // publish written inline
      // absorb edge (r,q): kc = fresh h in LDS; prefetch next level meanwhile
      const int r2p = parent_of[r];
      bool s2 = false;
      if (r2p >= 0) {
        const int gr2 = node_group[r2p];
        s2 = (group_start[gr2+1] - group_start[gr2] == 1);
      }
      float aN2 = 0.f, rN2 = 0.f;
      if (s2 && rowOK) {
        aN2 = __half2float(A_all[(size_t)r2p*AST + t]);
        rN2 = __half2float(R_all[(size_t)r*AST + t]);
      }
      if (t < 150) hreg = 0.f;
      unsigned short* pubp = nullptr; float* outp = nullptr;
      if (r == 0) outp = d_out;
      else if (!s2) pubp = (unsigned short*)(K_pack + (size_t)r*KST);
      DO_STEP(aN + rN, h_pack, pubp, outp, -1)
      q = r; r = r2p; single = s2; aN = aN2; rN = rN2;
    }
  }
}

// ---------------------------------------------------------------------------
extern "C" void kernel_launch(void* const* d_in, const int* in_sizes, int n_in,
                              void* d_out, int out_size, void* d_ws, size_t ws_size,
                              hipStream_t stream)
{
  const float* w_emb   = (const float*)d_in[0];
  const float* tag_emb = (const float*)d_in[1];
  const float* rel_emb = (const float*)d_in[2];
  const float* leaf_h  = (const float*)d_in[3];
  const float* leaf_W  = (const float*)d_in[4];
  const float* leaf_U  = (const float*)d_in[5];
  const float* leaf_b  = (const float*)d_in[6];
  const float* node_W  = (const float*)d_in[7];
  const float* node_U  = (const float*)d_in[8];
  const float* node_b  = (const float*)d_in[9];
  const float* at_Wb   = (const float*)d_in[10];
  const float* at_bb   = (const float*)d_in[11];
  const float* at_Wa   = (const float*)d_in[12];
  const float* at_ba   = (const float*)d_in[13];
  const int*   edges   = (const int*)d_in[14];
  const int*   leaf_ids= (const int*)d_in[15];
  float* out = (float*)d_out;

  const int N = in_sizes[0]/300;
  const int E = in_sizes[14]/2;
  const int L = in_sizes[15];

  char* ws = (char*)d_ws;
  size_t off = 0;
  auto take = [&](size_t bytes) -> char* {
    char* p = ws + off;
    off = (off + bytes + 255) & ~(size_t)255;
    return p;
  };
  size_t zbytes = 256 + (size_t)4*N;           // ctrl + has_child
  char* zbase       = take(zbytes);
  int*  ctrl        = (int*)zbase;             // [0]=pop counter, [1]=n_groups
  int*  has_child   = (int*)(zbase + 256);
  int*  parent_of   = (int*)take((size_t)4*N);
  int*  node_group  = (int*)take((size_t)4*N);
  int*  group_start = (int*)take((size_t)4*(N+1));
  uint32_t* UW      = (uint32_t*)take((size_t)4*NP2*WST);
  uint32_t* WK      = (uint32_t*)take((size_t)4*NP2*WST);
  float* NWT        = (float*)take((size_t)4*320*ROWS);
  float* LWT        = (float*)take((size_t)4*320*450);
  float* RWT        = (float*)take((size_t)4*20*ROWS);
  float* uh_leaf    = (float*)take((size_t)4*456);
  __half* A_all     = (__half*)take((size_t)2*((size_t)N*AST + 64));
  __half* R_all     = (__half*)take((size_t)2*((size_t)N*AST + 64));
  uint32_t* K_pack  = (uint32_t*)take((size_t)4*(size_t)N*KST);
  (void)ws_size; (void)n_in; (void)out_size;

  hipMemsetAsync(zbase, 0, zbytes, stream);
  hipMemsetAsync(K_pack, 0xFF, (size_t)4*(size_t)N*KST, stream);  // sentinel init

  const int TOT = E + NP2*WST + NP2*WST + 320*ROWS + 320*450 + 20*ROWS;
  const int GA  = 2 + (TOT + 1023)/1024;
  k_prepA<<<GA, 1024, 0, stream>>>(edges, E, node_U, node_W, at_Wb, leaf_W,
                                   leaf_U, leaf_h, leaf_b, uh_leaf,
                                   UW, WK, NWT, LWT, RWT, parent_of, has_child,
                                   group_start, ctrl, node_group);

  const int SB = (N + 15)/16;          // static blocks (covers NG <= N groups)
  const int LB = (L + 7)/8;            // leaf blocks
  const int RB = (N + 31)/32;          // rel blocks
  k_bulkB<<<SB + LB + RB, 512, 0, stream>>>(edges, group_start, ctrl,
                                            w_emb, tag_emb, NWT, node_b, at_bb, A_all,
                                            leaf_ids, LWT, uh_leaf, leaf_h, K_pack, L,
                                            rel_emb, RWT, R_all, N, SB, LB);

  k_worker<<<256, 512, 0, stream>>>(edges, at_Wa, at_ba, UW, WK, A_all, R_all,
                                    K_pack, ctrl, group_start, parent_of,
                                    node_group, has_child, out);
}